// Round 8
// baseline (1942.630 us; speedup 1.0000x reference)
//
#include <hip/hip_runtime.h>

#define H    32
#define SEQ  1440
#define NT   (SEQ - 1)   // step 1439 is dead code (only h2[:, :1439] is consumed)
#define INP  11
#define TC   64          // timesteps per chunk (x staging + deferred FC)

#define LOG2E 1.44269504f

__device__ __forceinline__ float rcp_fast(float x)  { return __builtin_amdgcn_rcpf(x); }
__device__ __forceinline__ float exp2_fast(float x) { return __builtin_amdgcn_exp2f(x); }
__device__ __forceinline__ float tanh_f(float x) {
    // tanh(x) = 2/(1+exp2(-2*log2e*x)) - 1
    return fmaf(2.f, rcp_fast(1.f + exp2_fast(x * (-2.f * LOG2E))), -1.f);
}

// Block = 256 threads (4 waves) = TWO batch samples.
// Lane l = [kh:1][q:2][m:3]; wave wv. Thread owns k-half kh of gate row
// r = q*32 + (wv*8+m), and processes BOTH samples -> each weight register
// feeds 2 FMAs per step (amortizes any residual reload cost).
// Weights/thread: wh0[16] + wx[6] + wi1[16] + wh1[16] = 54 regs (~105 peak live).
//
// LDS is deliberately padded to ~66KB: the register allocator derives its
// occupancy target from LDS/block-size limits (measured: 22KB/256t -> 7 blk/CU
// -> 72 VGPRs granted; 12.8KB/256t -> 64). At 66KB -> 2 blocks/CU -> 2
// waves/SIMD -> 256-VGPR budget, so the weight set stays resident. The grid
// (512 blocks) imposes 2 blocks/CU anyway, so no occupancy is lost.
__global__
__attribute__((amdgpu_flat_work_group_size(256, 256)))
__attribute__((amdgpu_waves_per_eu(2, 2)))
void lstm_fused_kernel(const float* __restrict__ x,
                       const float* __restrict__ Wih0, const float* __restrict__ Whh0,
                       const float* __restrict__ bih0, const float* __restrict__ bhh0,
                       const float* __restrict__ Wih1, const float* __restrict__ Whh1,
                       const float* __restrict__ bih1, const float* __restrict__ bhh1,
                       const float* __restrict__ fc1w_g, const float* __restrict__ fc1b_g,
                       const float* __restrict__ fc2w_g, const float* __restrict__ fc2b_g,
                       float* __restrict__ out)
{
    __shared__ float h0s[2][2][H];      // [parity][sample][unit]
    __shared__ float h1s[2][2][H];
    __shared__ float xs[2][TC][12];     // [sample][t][i], padded 11->12
    __shared__ float h1c[2][TC][36];    // [sample][t][unit(+pad)] for deferred FC
    __shared__ float ldspad[10240];     // 40KB occupancy-shaping pad (volatile-kept)

    const int tid = threadIdx.x;
    ((volatile float*)ldspad)[tid] = 0.f;   // keep the pad allocated

    const int l   = tid & 63;
    const int wv  = tid >> 6;          // 0..3
    const int m   = l & 7;
    const int q   = (l >> 3) & 3;      // gate: 0=i 1=f 2=g 3=o
    const int kh  = l >> 5;            // k-half
    const int jj  = wv * 8 + m;        // hidden unit 0..31
    const int r   = q * 32 + jj;       // gate row 0..127
    const int b   = blockIdx.x;        // sample pair

    const float gsl = ((q == 2) ? 2.f : 1.f) * LOG2E;  // fold tanh 2x + log2e
    const float am  = (q == 2) ? 2.f : 1.f;
    const float ab  = (q == 2) ? -1.f : 0.f;

    // ---- weights -> registers: k-half kh of each row, pre-scaled ----
    float wh0[16], wi1[16], wh1[16], wx[6];
    #pragma unroll
    for (int k = 0; k < 16; ++k) {
        wh0[k] = Whh0[r * H + kh * 16 + k] * gsl;
        wi1[k] = Wih1[r * H + kh * 16 + k] * gsl;
        wh1[k] = Whh1[r * H + kh * 16 + k] * gsl;
    }
    #pragma unroll
    for (int i = 0; i < 6; ++i) {
        const int gi = kh * 6 + i;
        wx[i] = (gi < INP) ? Wih0[r * INP + gi] * gsl : 0.f;
    }
    const float bs0 = (kh == 0) ? (bih0[r] + bhh0[r]) * gsl : 0.f;
    const float bs1 = (kh == 0) ? (bih1[r] + bhh1[r]) * gsl : 0.f;

    if (tid < 2 * H)          h0s[0][tid >> 5][tid & 31] = 0.f;
    else if (tid < 4 * H)     h1s[0][(tid >> 5) & 1][tid & 31] = 0.f;
    float c0[2] = {0.f, 0.f}, c1[2] = {0.f, 0.f};

    const float* xb0  = x + ((size_t)(2 * b) + 0) * INP * SEQ;
    const float* xb1  = x + ((size_t)(2 * b) + 1) * INP * SEQ;
    float*       outb = out + (size_t)(2 * b) * NT;

    __syncthreads();

    for (int cbase = 0; cbase < NT; cbase += TC) {
        const int clen = min(TC, NT - cbase);

        // ---- stage x for both samples (coalesced over t) ----
        {
            const int col = tid & 63;
            const int rw  = tid >> 6;
            if (col < clen) {
                #pragma unroll
                for (int ib = 0; ib < 3; ++ib) {
                    const int row = ib * 4 + rw;
                    xs[0][col][row] = (row < INP) ? xb0[row * SEQ + cbase + col] : 0.f;
                    xs[1][col][row] = (row < INP) ? xb1[row * SEQ + cbase + col] : 0.f;
                }
            }
        }
        __syncthreads();

        for (int tc = 0; tc < clen; ++tc) {
            const int p = (cbase + tc) & 1;   // h double-buffer parity

            // ================= layer 0, both samples =================
            #pragma unroll
            for (int s = 0; s < 2; ++s) {
                const float2* xv = (const float2*)&xs[s][tc][kh * 6];
                const float4* hv = (const float4*)&h0s[p][s][kh * 16];
                float a0 = bs0, a1 = 0.f;
                float2 x0 = xv[0], x1 = xv[1], x2 = xv[2];
                a0 = fmaf(wx[0], x0.x, a0);  a1 = fmaf(wx[1], x0.y, a1);
                a0 = fmaf(wx[2], x1.x, a0);  a1 = fmaf(wx[3], x1.y, a1);
                a0 = fmaf(wx[4], x2.x, a0);  a1 = fmaf(wx[5], x2.y, a1);
                float4 h0 = hv[0], h1v = hv[1], h2v = hv[2], h3v = hv[3];
                a0 = fmaf(wh0[0],  h0.x,  a0);  a1 = fmaf(wh0[1],  h0.y,  a1);
                a0 = fmaf(wh0[2],  h0.z,  a0);  a1 = fmaf(wh0[3],  h0.w,  a1);
                a0 = fmaf(wh0[4],  h1v.x, a0);  a1 = fmaf(wh0[5],  h1v.y, a1);
                a0 = fmaf(wh0[6],  h1v.z, a0);  a1 = fmaf(wh0[7],  h1v.w, a1);
                a0 = fmaf(wh0[8],  h2v.x, a0);  a1 = fmaf(wh0[9],  h2v.y, a1);
                a0 = fmaf(wh0[10], h2v.z, a0);  a1 = fmaf(wh0[11], h2v.w, a1);
                a0 = fmaf(wh0[12], h3v.x, a0);  a1 = fmaf(wh0[13], h3v.y, a1);
                a0 = fmaf(wh0[14], h3v.z, a0);  a1 = fmaf(wh0[15], h3v.w, a1);
                float a = a0 + a1;
                a += __shfl_xor(a, 32);                     // combine k-halves
                float act = fmaf(am, rcp_fast(1.f + exp2_fast(-a)), ab);
                float gf = __shfl_xor(act, 8);
                float gg = __shfl_xor(act, 16);
                float go = __shfl_xor(act, 24);
                if ((l & 56) == 0) {                        // q==0 && kh==0
                    c0[s] = fmaf(gf, c0[s], act * gg);
                    h0s[p ^ 1][s][jj] = go * tanh_f(c0[s]);
                }
            }
            __syncthreads();   // new h0 visible

            // ================= layer 1, both samples =================
            #pragma unroll
            for (int s = 0; s < 2; ++s) {
                const float4* iv = (const float4*)&h0s[p ^ 1][s][kh * 16]; // new h0
                const float4* hv = (const float4*)&h1s[p][s][kh * 16];     // old h1
                float a0 = bs1, a1 = 0.f, a2 = 0.f, a3 = 0.f;
                float4 i0 = iv[0], i1 = iv[1], i2 = iv[2], i3 = iv[3];
                float4 g0 = hv[0], g1 = hv[1], g2 = hv[2], g3 = hv[3];
                a0 = fmaf(wi1[0],  i0.x, a0);  a1 = fmaf(wi1[1],  i0.y, a1);
                a2 = fmaf(wi1[2],  i0.z, a2);  a3 = fmaf(wi1[3],  i0.w, a3);
                a0 = fmaf(wi1[4],  i1.x, a0);  a1 = fmaf(wi1[5],  i1.y, a1);
                a2 = fmaf(wi1[6],  i1.z, a2);  a3 = fmaf(wi1[7],  i1.w, a3);
                a0 = fmaf(wi1[8],  i2.x, a0);  a1 = fmaf(wi1[9],  i2.y, a1);
                a2 = fmaf(wi1[10], i2.z, a2);  a3 = fmaf(wi1[11], i2.w, a3);
                a0 = fmaf(wi1[12], i3.x, a0);  a1 = fmaf(wi1[13], i3.y, a1);
                a2 = fmaf(wi1[14], i3.z, a2);  a3 = fmaf(wi1[15], i3.w, a3);
                a0 = fmaf(wh1[0],  g0.x, a0);  a1 = fmaf(wh1[1],  g0.y, a1);
                a2 = fmaf(wh1[2],  g0.z, a2);  a3 = fmaf(wh1[3],  g0.w, a3);
                a0 = fmaf(wh1[4],  g1.x, a0);  a1 = fmaf(wh1[5],  g1.y, a1);
                a2 = fmaf(wh1[6],  g1.z, a2);  a3 = fmaf(wh1[7],  g1.w, a3);
                a0 = fmaf(wh1[8],  g2.x, a0);  a1 = fmaf(wh1[9],  g2.y, a1);
                a2 = fmaf(wh1[10], g2.z, a2);  a3 = fmaf(wh1[11], g2.w, a3);
                a0 = fmaf(wh1[12], g3.x, a0);  a1 = fmaf(wh1[13], g3.y, a1);
                a2 = fmaf(wh1[14], g3.z, a2);  a3 = fmaf(wh1[15], g3.w, a3);
                float a = (a0 + a1) + (a2 + a3);
                a += __shfl_xor(a, 32);
                float act = fmaf(am, rcp_fast(1.f + exp2_fast(-a)), ab);
                float gf = __shfl_xor(act, 8);
                float gg = __shfl_xor(act, 16);
                float go = __shfl_xor(act, 24);
                if ((l & 56) == 0) {
                    c1[s] = fmaf(gf, c1[s], act * gg);
                    float hn = go * tanh_f(c1[s]);
                    h1s[p ^ 1][s][jj] = hn;
                    h1c[s][tc][jj]    = hn;
                }
            }
            __syncthreads();   // h1/h1c visible
        }

        // ---- deferred FC head: half the block per sample ----
        {
            const int sfc = tid >> 7;          // sample
            const int ht  = tid & 127;
            const int u   = ht & 15;           // FC unit
            float fcw[H];                       // chunk-local
            #pragma unroll
            for (int k = 0; k < H; ++k) fcw[k] = fc1w_g[u * H + k];
            const float fcb = fc1b_g[u];
            const float f2w = fc2w_g[u];
            const float f2b = fc2b_g[0];
            float* outc = outb + (size_t)sfc * NT + cbase;
            #pragma unroll
            for (int rep = 0; rep < 8; ++rep) {
                const int tcl = (ht >> 4) + 8 * rep;
                if (tcl < clen) {
                    const float4* hv = (const float4*)h1c[sfc][tcl];
                    float a0 = fcb, a1 = 0.f;
                    #pragma unroll
                    for (int kk = 0; kk < 4; ++kk) {
                        float4 ha = hv[kk], hb = hv[kk + 4];
                        a0 = fmaf(fcw[4*kk+0],    ha.x, a0); a1 = fmaf(fcw[4*kk+1],    ha.y, a1);
                        a0 = fmaf(fcw[4*kk+2],    ha.z, a0); a1 = fmaf(fcw[4*kk+3],    ha.w, a1);
                        a0 = fmaf(fcw[16+4*kk+0], hb.x, a0); a1 = fmaf(fcw[16+4*kk+1], hb.y, a1);
                        a0 = fmaf(fcw[16+4*kk+2], hb.z, a0); a1 = fmaf(fcw[16+4*kk+3], hb.w, a1);
                    }
                    float yv = tanh_f(a0 + a1) * f2w;
                    yv += __shfl_xor(yv, 1);
                    yv += __shfl_xor(yv, 2);
                    yv += __shfl_xor(yv, 4);
                    yv += __shfl_xor(yv, 8);
                    if (u == 0) outc[tcl] = yv + f2b;
                }
            }
        }
        __syncthreads();   // h1c reads done before next chunk overwrites
    }
}

extern "C" void kernel_launch(void* const* d_in, const int* in_sizes, int n_in,
                              void* d_out, int out_size, void* d_ws, size_t ws_size,
                              hipStream_t stream)
{
    const float* x    = (const float*)d_in[0];
    const float* Wih0 = (const float*)d_in[1];
    const float* Whh0 = (const float*)d_in[2];
    const float* bih0 = (const float*)d_in[3];
    const float* bhh0 = (const float*)d_in[4];
    const float* Wih1 = (const float*)d_in[5];
    const float* Whh1 = (const float*)d_in[6];
    const float* bih1 = (const float*)d_in[7];
    const float* bhh1 = (const float*)d_in[8];
    const float* fc1w = (const float*)d_in[9];
    const float* fc1b = (const float*)d_in[10];
    const float* fc2w = (const float*)d_in[11];
    const float* fc2b = (const float*)d_in[12];
    float* out = (float*)d_out;

    const int B = in_sizes[0] / (INP * SEQ);   // 1024
    dim3 grid(B / 2), block(256);
    hipLaunchKernelGGL(lstm_fused_kernel, grid, block, 0, stream,
                       x, Wih0, Whh0, bih0, bhh0, Wih1, Whh1, bih1, bhh1,
                       fc1w, fc1b, fc2w, fc2b, out);
}

// Round 9
// 1572.745 us; speedup vs baseline: 1.2352x; 1.2352x over previous
//
#include <hip/hip_runtime.h>

#define H    32
#define SEQ  1440
#define NT   (SEQ - 1)   // output steps st = 0..1438; phase 1439 only finishes L1
#define INP  11
#define TC   64          // x staging / FC chunk
#define LOG2E 1.44269504f

__device__ __forceinline__ float rcp_fast(float x)  { return __builtin_amdgcn_rcpf(x); }
__device__ __forceinline__ float exp2_fast(float x) { return __builtin_amdgcn_exp2f(x); }
__device__ __forceinline__ float tanh_f(float x) {
    // tanh(x) = 2/(1+exp2(-2*log2e*x)) - 1
    return fmaf(2.f, rcp_fast(1.f + exp2_fast(x * (-2.f * LOG2E))), -1.f);
}

// Block = 512 threads (8 waves) = FOUR batch samples; grid = 256 = 1 block/CU.
// Crew split: tid<256 = layer-0 crew, tid>=256 = layer-1 crew. Within a crew,
// thread (sp, w2, l): sample pair sp (samples 2sp,2sp+1), gate q=l>>4,
// unit jj=w2*16+(l&15), row r=q*32+jj. Weights (shared wA/wB arrays across the
// divergent crews -> one allocation): L0: wA=Whh0 row(32), wB=Wih0 row(11,
// zero-padded); L1: wA=Wih1 row(32), wB=Whh1 row(32).
// KEY: dot loops are SAMPLE-INNER -> each weight's 2 uses are adjacent, so a
// weight the allocator parks (AGPR/L2; grants observed 64-112 regardless of
// hints) costs 1 reload per 2 FMAs instead of 1:1 -> bloat ceiling 1.5x.
// Pipeline (1 barrier/phase): phase p: L0 computes h0[p], L1 computes h1[p-1].
// Parity: h0[t],h1[t] live in buf (t&1)^1; with pb=p&1: L0 reads h0[p-1]@pb,
// writes h0[p]@pb^1; L1 reads h0[p-1]@pb, h1[p-2]@pb^1, writes h1[p-1]@pb.
// LDS ~88KB (h1c dominates) -> 1 block/CU at compile time = 2 waves/SIMD.
__global__
__attribute__((amdgpu_flat_work_group_size(512, 512)))
void lstm_fused_kernel(const float* __restrict__ x,
                       const float* __restrict__ Wih0, const float* __restrict__ Whh0,
                       const float* __restrict__ bih0, const float* __restrict__ bhh0,
                       const float* __restrict__ Wih1, const float* __restrict__ Whh1,
                       const float* __restrict__ bih1, const float* __restrict__ bhh1,
                       const float* __restrict__ fc1w_g, const float* __restrict__ fc1b_g,
                       const float* __restrict__ fc2w_g, const float* __restrict__ fc2b_g,
                       float* __restrict__ out)
{
    __shared__ float h0s[2][4][H];        // [buf][sample][unit]
    __shared__ float h1s[2][4][H];
    __shared__ float xs[4][TC][12];       // [sample][t][i], padded 11->12
    __shared__ float h1c[4][2][TC][36];   // [sample][chunk-parity][t][unit(+pad)]

    const int tid  = threadIdx.x;
    const int crew = tid >> 8;            // 0 = L0, 1 = L1
    const int sp   = (tid >> 7) & 1;      // sample pair
    const int sA   = sp * 2, sB = sp * 2 + 1;
    const int l    = tid & 63;
    const int w2   = (tid >> 6) & 1;
    const int q    = l >> 4;              // gate 0=i 1=f 2=g 3=o
    const int jj   = w2 * 16 + (l & 15);  // hidden unit
    const int r    = q * 32 + jj;         // gate row
    const int b    = blockIdx.x;

    const float gsl = ((q == 2) ? 2.f : 1.f) * LOG2E;   // fold tanh 2x + log2e
    const float am  = (q == 2) ? 2.f : 1.f;
    const float ab  = (q == 2) ? -1.f : 0.f;

    // ---- weights -> registers (pre-scaled); one shared allocation for both crews ----
    float wA[H], wB[H], bs;
    if (crew == 0) {
        #pragma unroll
        for (int k = 0; k < H; ++k) wA[k] = Whh0[r * H + k] * gsl;
        #pragma unroll
        for (int k = 0; k < H; ++k) wB[k] = (k < INP) ? Wih0[r * INP + k] * gsl : 0.f;
        bs = (bih0[r] + bhh0[r]) * gsl;
    } else {
        #pragma unroll
        for (int k = 0; k < H; ++k) {
            wA[k] = Wih1[r * H + k] * gsl;
            wB[k] = Whh1[r * H + k] * gsl;
        }
        bs = (bih1[r] + bhh1[r]) * gsl;
    }

    if (tid < 128)       h0s[0][tid >> 5][tid & 31] = 0.f;
    else if (tid < 256)  h1s[0][(tid >> 5) & 3][tid & 31] = 0.f;
    float c[2] = {0.f, 0.f};   // cell states (c0 for L0 crew, c1 for L1 crew), q==0 lanes

    float* outb = out + (size_t)(4 * b) * NT;

    for (int cb = 0; cb < SEQ; cb += TC) {
        const int plen = min(TC, SEQ - cb);

        // ---- stage x for 4 samples (coalesced over t); 8 row-slots x 64 cols ----
        {
            const int col = tid & 63;
            const int rw  = tid >> 6;            // 0..7
            const int ss  = rw >> 1;             // sample
            const int hf  = rw & 1;              // row half (0: rows 0-5, 1: rows 6-11)
            if (col < plen) {
                const float* xbS = x + (size_t)(4 * b + ss) * INP * SEQ;
                #pragma unroll
                for (int ib = 0; ib < 6; ++ib) {
                    const int row = hf * 6 + ib;
                    xs[ss][col][row] = (row < INP) ? xbS[row * SEQ + cb + col] : 0.f;
                }
            }
        }
        __syncthreads();

        for (int pc = 0; pc < plen; ++pc) {
            const int p  = cb + pc;
            const int pb = p & 1;

            if (crew == 0) {
                // ---------- layer 0: h0[p] for samples sA,sB (skip dead p=1439) ----------
                if (p < NT) {
                    const float4* xvA = (const float4*)xs[sA][pc];
                    const float4* xvB = (const float4*)xs[sB][pc];
                    const float4* hA  = (const float4*)h0s[pb][sA];
                    const float4* hB  = (const float4*)h0s[pb][sB];
                    float aA0 = bs, aA1 = 0.f, aB0 = bs, aB1 = 0.f;
                    #pragma unroll
                    for (int kk = 0; kk < 3; ++kk) {       // x part (wB[11]=0)
                        float4 vA = xvA[kk], vB = xvB[kk];
                        aA0 = fmaf(wB[4*kk+0], vA.x, aA0); aB0 = fmaf(wB[4*kk+0], vB.x, aB0);
                        aA1 = fmaf(wB[4*kk+1], vA.y, aA1); aB1 = fmaf(wB[4*kk+1], vB.y, aB1);
                        aA0 = fmaf(wB[4*kk+2], vA.z, aA0); aB0 = fmaf(wB[4*kk+2], vB.z, aB0);
                        aA1 = fmaf(wB[4*kk+3], vA.w, aA1); aB1 = fmaf(wB[4*kk+3], vB.w, aB1);
                    }
                    #pragma unroll
                    for (int kk = 0; kk < 8; ++kk) {       // recurrent part
                        float4 vA = hA[kk], vB = hB[kk];
                        aA0 = fmaf(wA[4*kk+0], vA.x, aA0); aB0 = fmaf(wA[4*kk+0], vB.x, aB0);
                        aA1 = fmaf(wA[4*kk+1], vA.y, aA1); aB1 = fmaf(wA[4*kk+1], vB.y, aB1);
                        aA0 = fmaf(wA[4*kk+2], vA.z, aA0); aB0 = fmaf(wA[4*kk+2], vB.z, aB0);
                        aA1 = fmaf(wA[4*kk+3], vA.w, aA1); aB1 = fmaf(wA[4*kk+3], vB.w, aB1);
                    }
                    float actA = fmaf(am, rcp_fast(1.f + exp2_fast(-(aA0 + aA1))), ab);
                    float actB = fmaf(am, rcp_fast(1.f + exp2_fast(-(aB0 + aB1))), ab);
                    float fA = __shfl_xor(actA, 16), gA = __shfl_xor(actA, 32), oA = __shfl_xor(actA, 48);
                    float fB = __shfl_xor(actB, 16), gB = __shfl_xor(actB, 32), oB = __shfl_xor(actB, 48);
                    if (q == 0) {
                        c[0] = fmaf(fA, c[0], actA * gA);
                        h0s[pb ^ 1][sA][jj] = oA * tanh_f(c[0]);
                        c[1] = fmaf(fB, c[1], actB * gB);
                        h0s[pb ^ 1][sB][jj] = oB * tanh_f(c[1]);
                    }
                }
            } else {
                // ---------- layer 1: h1[st], st = p-1, samples sA,sB ----------
                if (p >= 1) {
                    const int st = p - 1;
                    const float4* iA = (const float4*)h0s[pb][sA];      // h0[st]
                    const float4* iB = (const float4*)h0s[pb][sB];
                    const float4* hA = (const float4*)h1s[pb ^ 1][sA];  // h1[st-1]
                    const float4* hB = (const float4*)h1s[pb ^ 1][sB];
                    float aA0 = bs, aA1 = 0.f, aB0 = bs, aB1 = 0.f;
                    #pragma unroll
                    for (int kk = 0; kk < 8; ++kk) {       // input part (new h0)
                        float4 vA = iA[kk], vB = iB[kk];
                        aA0 = fmaf(wA[4*kk+0], vA.x, aA0); aB0 = fmaf(wA[4*kk+0], vB.x, aB0);
                        aA1 = fmaf(wA[4*kk+1], vA.y, aA1); aB1 = fmaf(wA[4*kk+1], vB.y, aB1);
                        aA0 = fmaf(wA[4*kk+2], vA.z, aA0); aB0 = fmaf(wA[4*kk+2], vB.z, aB0);
                        aA1 = fmaf(wA[4*kk+3], vA.w, aA1); aB1 = fmaf(wA[4*kk+3], vB.w, aB1);
                    }
                    #pragma unroll
                    for (int kk = 0; kk < 8; ++kk) {       // recurrent part (old h1)
                        float4 vA = hA[kk], vB = hB[kk];
                        aA0 = fmaf(wB[4*kk+0], vA.x, aA0); aB0 = fmaf(wB[4*kk+0], vB.x, aB0);
                        aA1 = fmaf(wB[4*kk+1], vA.y, aA1); aB1 = fmaf(wB[4*kk+1], vB.y, aB1);
                        aA0 = fmaf(wB[4*kk+2], vA.z, aA0); aB0 = fmaf(wB[4*kk+2], vB.z, aB0);
                        aA1 = fmaf(wB[4*kk+3], vA.w, aA1); aB1 = fmaf(wB[4*kk+3], vB.w, aB1);
                    }
                    float actA = fmaf(am, rcp_fast(1.f + exp2_fast(-(aA0 + aA1))), ab);
                    float actB = fmaf(am, rcp_fast(1.f + exp2_fast(-(aB0 + aB1))), ab);
                    float fA = __shfl_xor(actA, 16), gA = __shfl_xor(actA, 32), oA = __shfl_xor(actA, 48);
                    float fB = __shfl_xor(actB, 16), gB = __shfl_xor(actB, 32), oB = __shfl_xor(actB, 48);
                    if (q == 0) {
                        const int par = (st >> 6) & 1, tt = st & 63;
                        c[0] = fmaf(fA, c[0], actA * gA);
                        float hnA = oA * tanh_f(c[0]);
                        h1s[pb][sA][jj] = hnA;
                        h1c[sA][par][tt][jj] = hnA;
                        c[1] = fmaf(fB, c[1], actB * gB);
                        float hnB = oB * tanh_f(c[1]);
                        h1s[pb][sB][jj] = hnB;
                        h1c[sB][par][tt][jj] = hnB;
                    }
                }
            }
            __syncthreads();   // the ONLY barrier per phase

            // ---- deferred FC for the just-completed chunk C-1 (all 512 threads) ----
            // Chunk C-1's last element (st=cb-1) was written this phase, pre-barrier.
            if (pc == 0 && cb >= TC) {
                const int u   = l & 15;                 // FC unit
                const int gcb = (tid >> 6) * 4 + (l >> 4);   // 0..31 = sample*8 + slot
                const int fs  = gcb >> 3, slot = gcb & 7;
                const float (*hcp)[36] = h1c[fs][((cb >> 6) - 1) & 1];
                float fcw[H];                            // chunk-local
                #pragma unroll
                for (int k = 0; k < H; ++k) fcw[k] = fc1w_g[u * H + k];
                const float fcb = fc1b_g[u], f2w = fc2w_g[u], f2b = fc2b_g[0];
                float* outc = outb + (size_t)fs * NT + (cb - TC);
                #pragma unroll
                for (int rep = 0; rep < 8; ++rep) {
                    const int t2 = slot + 8 * rep;
                    const float4* hv = (const float4*)hcp[t2];
                    float a0 = fcb, a1 = 0.f;
                    #pragma unroll
                    for (int kk = 0; kk < 8; ++kk) {
                        float4 v = hv[kk];
                        a0 = fmaf(fcw[4*kk+0], v.x, a0); a1 = fmaf(fcw[4*kk+1], v.y, a1);
                        a0 = fmaf(fcw[4*kk+2], v.z, a0); a1 = fmaf(fcw[4*kk+3], v.w, a1);
                    }
                    float z = tanh_f(a0 + a1) * f2w;
                    z += __shfl_xor(z, 1);  z += __shfl_xor(z, 2);
                    z += __shfl_xor(z, 4);  z += __shfl_xor(z, 8);
                    if (u == 0) outc[t2] = z + f2b;
                }
            }
        }
    }

    // ---- tail FC: st in [1408, 1438] (31 entries), chunk parity 0 ----
    {
        const int tbase = 1408, tlen = NT - tbase;       // 31
        const int u   = l & 15;
        const int gcb = (tid >> 6) * 4 + (l >> 4);
        const int fs  = gcb >> 3, slot = gcb & 7;
        const float (*hcp)[36] = h1c[fs][(tbase >> 6) & 1];
        float fcw[H];
        #pragma unroll
        for (int k = 0; k < H; ++k) fcw[k] = fc1w_g[u * H + k];
        const float fcb = fc1b_g[u], f2w = fc2w_g[u], f2b = fc2b_g[0];
        float* outc = outb + (size_t)fs * NT + tbase;
        #pragma unroll
        for (int rep = 0; rep < 8; ++rep) {
            const int t2 = slot + 8 * rep;
            if (t2 < tlen) {
                const float4* hv = (const float4*)hcp[t2];
                float a0 = fcb, a1 = 0.f;
                #pragma unroll
                for (int kk = 0; kk < 8; ++kk) {
                    float4 v = hv[kk];
                    a0 = fmaf(fcw[4*kk+0], v.x, a0); a1 = fmaf(fcw[4*kk+1], v.y, a1);
                    a0 = fmaf(fcw[4*kk+2], v.z, a0); a1 = fmaf(fcw[4*kk+3], v.w, a1);
                }
                float z = tanh_f(a0 + a1) * f2w;
                z += __shfl_xor(z, 1);  z += __shfl_xor(z, 2);
                z += __shfl_xor(z, 4);  z += __shfl_xor(z, 8);
                if (u == 0) outc[t2] = z + f2b;
            }
        }
    }
}

extern "C" void kernel_launch(void* const* d_in, const int* in_sizes, int n_in,
                              void* d_out, int out_size, void* d_ws, size_t ws_size,
                              hipStream_t stream)
{
    const float* x    = (const float*)d_in[0];
    const float* Wih0 = (const float*)d_in[1];
    const float* Whh0 = (const float*)d_in[2];
    const float* bih0 = (const float*)d_in[3];
    const float* bhh0 = (const float*)d_in[4];
    const float* Wih1 = (const float*)d_in[5];
    const float* Whh1 = (const float*)d_in[6];
    const float* bih1 = (const float*)d_in[7];
    const float* bhh1 = (const float*)d_in[8];
    const float* fc1w = (const float*)d_in[9];
    const float* fc1b = (const float*)d_in[10];
    const float* fc2w = (const float*)d_in[11];
    const float* fc2b = (const float*)d_in[12];
    float* out = (float*)d_out;

    const int B = in_sizes[0] / (INP * SEQ);   // 1024
    dim3 grid(B / 4), block(512);
    hipLaunchKernelGGL(lstm_fused_kernel, grid, block, 0, stream,
                       x, Wih0, Whh0, bih0, bhh0, Wih1, Whh1, bih1, bhh1,
                       fc1w, fc1b, fc2w, fc2b, out);
}

// Round 10
// 1414.974 us; speedup vs baseline: 1.3729x; 1.1115x over previous
//
#include <hip/hip_runtime.h>

#define H    32
#define SEQ  1440
#define NT   (SEQ - 1)   // output steps st = 0..1438; phase 1439 only finishes L1
#define INP  11
#define TC   64          // x staging / FC chunk
#define LOG2E 1.44269504f

__device__ __forceinline__ float rcp_fast(float x)  { return __builtin_amdgcn_rcpf(x); }
__device__ __forceinline__ float exp2_fast(float x) { return __builtin_amdgcn_exp2f(x); }
__device__ __forceinline__ float tanh_f(float x) {
    // tanh(x) = 2/(1+exp2(-2*log2e*x)) - 1
    return fmaf(2.f, rcp_fast(1.f + exp2_fast(x * (-2.f * LOG2E))), -1.f);
}

// Block = 256 threads (4 waves) = TWO batch samples; grid = 512 = 2 blocks/CU.
// Same structure as round 9 (lowest VALU issue: 530us) but with TWO independent
// barrier domains per CU instead of one: round 9's VALUBusy=34% showed the
// single-block-per-CU layout serialized the whole CU behind one barrier each
// phase. Halving the block re-enables cross-block latency hiding at identical
// wave count (8/CU = 2/SIMD).
// Crew split: tid<128 = layer-0 crew, tid>=128 = layer-1 crew. Thread (w2,l):
// gate q=l>>4, unit jj=w2*16+(l&15), row r=q*32+jj; processes BOTH samples
// sample-inner (each weight's 2 uses adjacent -> parked-weight reload cost
// amortized over 2 FMAs). Weights shared wA/wB arrays across divergent crews:
// L0: wA=Whh0 row(32), wB=Wih0 row(11, zero-padded); L1: wA=Wih1, wB=Whh1.
// Pipeline (1 barrier/phase): phase p: L0 computes h0[p], L1 computes h1[p-1].
// Parity: h0[t],h1[t] live in buf (t&1)^1; with pb=p&1: L0 reads h0[p-1]@pb,
// writes h0[p]@pb^1; L1 reads h0[p-1]@pb, h1[p-2]@pb^1, writes h1[p-1]@pb.
__global__
__attribute__((amdgpu_flat_work_group_size(256, 256)))
void lstm_fused_kernel(const float* __restrict__ x,
                       const float* __restrict__ Wih0, const float* __restrict__ Whh0,
                       const float* __restrict__ bih0, const float* __restrict__ bhh0,
                       const float* __restrict__ Wih1, const float* __restrict__ Whh1,
                       const float* __restrict__ bih1, const float* __restrict__ bhh1,
                       const float* __restrict__ fc1w_g, const float* __restrict__ fc1b_g,
                       const float* __restrict__ fc2w_g, const float* __restrict__ fc2b_g,
                       float* __restrict__ out)
{
    __shared__ float h0s[2][2][H];        // [buf][sample][unit]
    __shared__ float h1s[2][2][H];
    __shared__ float xs[2][TC][12];       // [sample][t][i], padded 11->12
    __shared__ float h1c[2][2][TC][36];   // [sample][chunk-parity][t][unit(+pad)]

    const int tid  = threadIdx.x;
    const int crew = tid >> 7;            // 0 = L0, 1 = L1
    const int l    = tid & 63;
    const int w2   = (tid >> 6) & 1;
    const int q    = l >> 4;              // gate 0=i 1=f 2=g 3=o
    const int jj   = w2 * 16 + (l & 15);  // hidden unit
    const int r    = q * 32 + jj;         // gate row
    const int b    = blockIdx.x;

    const float gsl = ((q == 2) ? 2.f : 1.f) * LOG2E;   // fold tanh 2x + log2e
    const float am  = (q == 2) ? 2.f : 1.f;
    const float ab  = (q == 2) ? -1.f : 0.f;

    // ---- weights -> registers (pre-scaled); one shared allocation for both crews ----
    float wA[H], wB[H], bs;
    if (crew == 0) {
        #pragma unroll
        for (int k = 0; k < H; ++k) wA[k] = Whh0[r * H + k] * gsl;
        #pragma unroll
        for (int k = 0; k < H; ++k) wB[k] = (k < INP) ? Wih0[r * INP + k] * gsl : 0.f;
        bs = (bih0[r] + bhh0[r]) * gsl;
    } else {
        #pragma unroll
        for (int k = 0; k < H; ++k) {
            wA[k] = Wih1[r * H + k] * gsl;
            wB[k] = Whh1[r * H + k] * gsl;
        }
        bs = (bih1[r] + bhh1[r]) * gsl;
    }

    if (tid < 64)        h0s[0][tid >> 5][tid & 31] = 0.f;
    else if (tid < 128)  h1s[0][(tid >> 5) & 1][tid & 31] = 0.f;
    float c[2] = {0.f, 0.f};   // cell states (c0 for L0 crew, c1 for L1 crew), q==0 lanes

    float* outb = out + (size_t)(2 * b) * NT;

    for (int cb = 0; cb < SEQ; cb += TC) {
        const int plen = min(TC, SEQ - cb);

        // ---- stage x for both samples (coalesced over t); 4 row-slots x 64 cols ----
        {
            const int col = tid & 63;
            const int rw  = tid >> 6;            // 0..3
            const int ss  = rw >> 1;             // sample
            const int hf  = rw & 1;              // row half (0: rows 0-5, 1: rows 6-11)
            if (col < plen) {
                const float* xbS = x + (size_t)(2 * b + ss) * INP * SEQ;
                #pragma unroll
                for (int ib = 0; ib < 6; ++ib) {
                    const int row = hf * 6 + ib;
                    xs[ss][col][row] = (row < INP) ? xbS[row * SEQ + cb + col] : 0.f;
                }
            }
        }
        __syncthreads();

        for (int pc = 0; pc < plen; ++pc) {
            const int p  = cb + pc;
            const int pb = p & 1;

            if (crew == 0) {
                // ---------- layer 0: h0[p] for samples 0,1 (skip dead p=1439) ----------
                if (p < NT) {
                    const float4* xvA = (const float4*)xs[0][pc];
                    const float4* xvB = (const float4*)xs[1][pc];
                    const float4* hA  = (const float4*)h0s[pb][0];
                    const float4* hB  = (const float4*)h0s[pb][1];
                    float aA0 = bs, aA1 = 0.f, aB0 = bs, aB1 = 0.f;
                    #pragma unroll
                    for (int kk = 0; kk < 3; ++kk) {       // x part (wB[11]=0)
                        float4 vA = xvA[kk], vB = xvB[kk];
                        aA0 = fmaf(wB[4*kk+0], vA.x, aA0); aB0 = fmaf(wB[4*kk+0], vB.x, aB0);
                        aA1 = fmaf(wB[4*kk+1], vA.y, aA1); aB1 = fmaf(wB[4*kk+1], vB.y, aB1);
                        aA0 = fmaf(wB[4*kk+2], vA.z, aA0); aB0 = fmaf(wB[4*kk+2], vB.z, aB0);
                        aA1 = fmaf(wB[4*kk+3], vA.w, aA1); aB1 = fmaf(wB[4*kk+3], vB.w, aB1);
                    }
                    #pragma unroll
                    for (int kk = 0; kk < 8; ++kk) {       // recurrent part
                        float4 vA = hA[kk], vB = hB[kk];
                        aA0 = fmaf(wA[4*kk+0], vA.x, aA0); aB0 = fmaf(wA[4*kk+0], vB.x, aB0);
                        aA1 = fmaf(wA[4*kk+1], vA.y, aA1); aB1 = fmaf(wA[4*kk+1], vB.y, aB1);
                        aA0 = fmaf(wA[4*kk+2], vA.z, aA0); aB0 = fmaf(wA[4*kk+2], vB.z, aB0);
                        aA1 = fmaf(wA[4*kk+3], vA.w, aA1); aB1 = fmaf(wA[4*kk+3], vB.w, aB1);
                    }
                    float actA = fmaf(am, rcp_fast(1.f + exp2_fast(-(aA0 + aA1))), ab);
                    float actB = fmaf(am, rcp_fast(1.f + exp2_fast(-(aB0 + aB1))), ab);
                    float fA = __shfl_xor(actA, 16), gA = __shfl_xor(actA, 32), oA = __shfl_xor(actA, 48);
                    float fB = __shfl_xor(actB, 16), gB = __shfl_xor(actB, 32), oB = __shfl_xor(actB, 48);
                    if (q == 0) {
                        c[0] = fmaf(fA, c[0], actA * gA);
                        h0s[pb ^ 1][0][jj] = oA * tanh_f(c[0]);
                        c[1] = fmaf(fB, c[1], actB * gB);
                        h0s[pb ^ 1][1][jj] = oB * tanh_f(c[1]);
                    }
                }
            } else {
                // ---------- layer 1: h1[st], st = p-1, samples 0,1 ----------
                if (p >= 1) {
                    const int st = p - 1;
                    const float4* iA = (const float4*)h0s[pb][0];      // h0[st]
                    const float4* iB = (const float4*)h0s[pb][1];
                    const float4* hA = (const float4*)h1s[pb ^ 1][0];  // h1[st-1]
                    const float4* hB = (const float4*)h1s[pb ^ 1][1];
                    float aA0 = bs, aA1 = 0.f, aB0 = bs, aB1 = 0.f;
                    #pragma unroll
                    for (int kk = 0; kk < 8; ++kk) {       // input part (new h0)
                        float4 vA = iA[kk], vB = iB[kk];
                        aA0 = fmaf(wA[4*kk+0], vA.x, aA0); aB0 = fmaf(wA[4*kk+0], vB.x, aB0);
                        aA1 = fmaf(wA[4*kk+1], vA.y, aA1); aB1 = fmaf(wA[4*kk+1], vB.y, aB1);
                        aA0 = fmaf(wA[4*kk+2], vA.z, aA0); aB0 = fmaf(wA[4*kk+2], vB.z, aB0);
                        aA1 = fmaf(wA[4*kk+3], vA.w, aA1); aB1 = fmaf(wA[4*kk+3], vB.w, aB1);
                    }
                    #pragma unroll
                    for (int kk = 0; kk < 8; ++kk) {       // recurrent part (old h1)
                        float4 vA = hA[kk], vB = hB[kk];
                        aA0 = fmaf(wB[4*kk+0], vA.x, aA0); aB0 = fmaf(wB[4*kk+0], vB.x, aB0);
                        aA1 = fmaf(wB[4*kk+1], vA.y, aA1); aB1 = fmaf(wB[4*kk+1], vB.y, aB1);
                        aA0 = fmaf(wB[4*kk+2], vA.z, aA0); aB0 = fmaf(wB[4*kk+2], vB.z, aB0);
                        aA1 = fmaf(wB[4*kk+3], vA.w, aA1); aB1 = fmaf(wB[4*kk+3], vB.w, aB1);
                    }
                    float actA = fmaf(am, rcp_fast(1.f + exp2_fast(-(aA0 + aA1))), ab);
                    float actB = fmaf(am, rcp_fast(1.f + exp2_fast(-(aB0 + aB1))), ab);
                    float fA = __shfl_xor(actA, 16), gA = __shfl_xor(actA, 32), oA = __shfl_xor(actA, 48);
                    float fB = __shfl_xor(actB, 16), gB = __shfl_xor(actB, 32), oB = __shfl_xor(actB, 48);
                    if (q == 0) {
                        const int par = (st >> 6) & 1, tt = st & 63;
                        c[0] = fmaf(fA, c[0], actA * gA);
                        float hnA = oA * tanh_f(c[0]);
                        h1s[pb][0][jj] = hnA;
                        h1c[0][par][tt][jj] = hnA;
                        c[1] = fmaf(fB, c[1], actB * gB);
                        float hnB = oB * tanh_f(c[1]);
                        h1s[pb][1][jj] = hnB;
                        h1c[1][par][tt][jj] = hnB;
                    }
                }
            }
            __syncthreads();   // the ONLY barrier per phase

            // ---- deferred FC for the just-completed chunk C-1 (all 256 threads) ----
            if (pc == 0 && cb >= TC) {
                const int u    = tid & 15;            // FC unit
                const int g16  = (tid >> 4) & 15;     // 16 groups: sample*8 + slot
                const int fs   = g16 >> 3, slot = g16 & 7;
                const float (*hcp)[36] = h1c[fs][((cb >> 6) - 1) & 1];
                float fcw[H];                          // chunk-local
                #pragma unroll
                for (int k = 0; k < H; ++k) fcw[k] = fc1w_g[u * H + k];
                const float fcb = fc1b_g[u], f2w = fc2w_g[u], f2b = fc2b_g[0];
                float* outc = outb + (size_t)fs * NT + (cb - TC);
                #pragma unroll
                for (int rep = 0; rep < 8; ++rep) {
                    const int t2 = slot + 8 * rep;
                    const float4* hv = (const float4*)hcp[t2];
                    float a0 = fcb, a1 = 0.f;
                    #pragma unroll
                    for (int kk = 0; kk < 8; ++kk) {
                        float4 v = hv[kk];
                        a0 = fmaf(fcw[4*kk+0], v.x, a0); a1 = fmaf(fcw[4*kk+1], v.y, a1);
                        a0 = fmaf(fcw[4*kk+2], v.z, a0); a1 = fmaf(fcw[4*kk+3], v.w, a1);
                    }
                    float z = tanh_f(a0 + a1) * f2w;
                    z += __shfl_xor(z, 1);  z += __shfl_xor(z, 2);
                    z += __shfl_xor(z, 4);  z += __shfl_xor(z, 8);
                    if (u == 0) outc[t2] = z + f2b;
                }
            }
        }
    }

    // ---- tail FC: st in [1408, 1438] (31 entries), chunk parity 0 ----
    {
        const int tbase = 1408, tlen = NT - tbase;       // 31
        const int u    = tid & 15;
        const int g16  = (tid >> 4) & 15;
        const int fs   = g16 >> 3, slot = g16 & 7;
        const float (*hcp)[36] = h1c[fs][(tbase >> 6) & 1];
        float fcw[H];
        #pragma unroll
        for (int k = 0; k < H; ++k) fcw[k] = fc1w_g[u * H + k];
        const float fcb = fc1b_g[u], f2w = fc2w_g[u], f2b = fc2b_g[0];
        float* outc = outb + (size_t)fs * NT + tbase;
        #pragma unroll
        for (int rep = 0; rep < 8; ++rep) {
            const int t2 = slot + 8 * rep;
            if (t2 < tlen) {
                const float4* hv = (const float4*)hcp[t2];
                float a0 = fcb, a1 = 0.f;
                #pragma unroll
                for (int kk = 0; kk < 8; ++kk) {
                    float4 v = hv[kk];
                    a0 = fmaf(fcw[4*kk+0], v.x, a0); a1 = fmaf(fcw[4*kk+1], v.y, a1);
                    a0 = fmaf(fcw[4*kk+2], v.z, a0); a1 = fmaf(fcw[4*kk+3], v.w, a1);
                }
                float z = tanh_f(a0 + a1) * f2w;
                z += __shfl_xor(z, 1);  z += __shfl_xor(z, 2);
                z += __shfl_xor(z, 4);  z += __shfl_xor(z, 8);
                if (u == 0) outc[t2] = z + f2b;
            }
        }
    }
}

extern "C" void kernel_launch(void* const* d_in, const int* in_sizes, int n_in,
                              void* d_out, int out_size, void* d_ws, size_t ws_size,
                              hipStream_t stream)
{
    const float* x    = (const float*)d_in[0];
    const float* Wih0 = (const float*)d_in[1];
    const float* Whh0 = (const float*)d_in[2];
    const float* bih0 = (const float*)d_in[3];
    const float* bhh0 = (const float*)d_in[4];
    const float* Wih1 = (const float*)d_in[5];
    const float* Whh1 = (const float*)d_in[6];
    const float* bih1 = (const float*)d_in[7];
    const float* bhh1 = (const float*)d_in[8];
    const float* fc1w = (const float*)d_in[9];
    const float* fc1b = (const float*)d_in[10];
    const float* fc2w = (const float*)d_in[11];
    const float* fc2b = (const float*)d_in[12];
    float* out = (float*)d_out;

    const int B = in_sizes[0] / (INP * SEQ);   // 1024
    dim3 grid(B / 2), block(256);
    hipLaunchKernelGGL(lstm_fused_kernel, grid, block, 0, stream,
                       x, Wih0, Whh0, bih0, bhh0, Wih1, Whh1, bih1, bhh1,
                       fc1w, fc1b, fc2w, fc2b, out);
}